// Round 4
// baseline (52.422 us; speedup 1.0000x reference)
//
#include <hip/hip_runtime.h>

#define SMOOTH 1e-5

typedef float f32x4 __attribute__((ext_vector_type(4)));
typedef int   i32x4 __attribute__((ext_vector_type(4)));

__device__ __forceinline__ f32x4 ldnt(const f32x4* p) {
    return __builtin_nontemporal_load(p);   // float stream: don't thrash L3
}

// Stage 1: streaming pass. Each block writes 4 double partials to ws[4*bid..]:
//   [0] c1 (count t==1), [1] s1 (sum p | t==1), [2] qa (sum p^2, all), [3] q1 (sum p^2 | t==1)
// Register software-pipeline: ping-pong groups A/B of 4 float4+int4 chunks so
// 8 loads are always in flight across the ~400-cycle compute of the other group.
__global__ __launch_bounds__(256, 4) void balanced_loss_stage1(
    const float* __restrict__ in, const int* __restrict__ tg,
    long long n, double* __restrict__ ws)
{
    const int nvec = (int)(n >> 2);  // float4 chunks (fits int32)
    float lc1 = 0.f, ls1 = 0.f, lqa = 0.f, lq1 = 0.f;

    const int tid    = blockIdx.x * blockDim.x + threadIdx.x;
    const int stride = gridDim.x * blockDim.x;
    const f32x4* __restrict__ in4 = (const f32x4*)in;
    const i32x4* __restrict__ tg4 = (const i32x4*)tg;

#define PROC(xv, tv)                                        \
    {                                                       \
        float e  = __expf(-(xv));                           \
        float p  = __builtin_amdgcn_rcpf(1.f + e);          \
        float pp = p * p;                                   \
        float ft = (float)(tv);  /* t in {0,1} */           \
        lqa += pp;                                          \
        lc1 += ft;                                          \
        ls1 += ft * p;                                      \
        lq1 += ft * pp;                                     \
    }
#define PROC4(X, T) { PROC((X).x, (T).x); PROC((X).y, (T).y); PROC((X).z, (T).z); PROC((X).w, (T).w); }

#define LOADG(X0,X1,X2,X3, T0,T1,T2,T3, base)               \
    {                                                       \
        int b0 = (base), b1 = b0 + stride;                  \
        int b2 = b1 + stride, b3 = b2 + stride;             \
        X0 = ldnt(in4 + b0);  T0 = tg4[b0];                 \
        X1 = ldnt(in4 + b1);  T1 = tg4[b1];                 \
        X2 = ldnt(in4 + b2);  T2 = tg4[b2];                 \
        X3 = ldnt(in4 + b3);  T3 = tg4[b3];                 \
        __builtin_amdgcn_sched_barrier(0);                  \
    }

    int i = tid;
    const int stride4 = 4 * stride;
    f32x4 xa0, xa1, xa2, xa3, xb0, xb1, xb2, xb3;
    i32x4 ta0, ta1, ta2, ta3, tb0, tb1, tb2, tb3;

    if (i + 3 * stride < nvec) {
        LOADG(xa0,xa1,xa2,xa3, ta0,ta1,ta2,ta3, i);
        i += stride4;
        for (;;) {
            if (i + 3 * stride >= nvec) {   // A is the last full group
                PROC4(xa0, ta0); PROC4(xa1, ta1); PROC4(xa2, ta2); PROC4(xa3, ta3);
                break;
            }
            LOADG(xb0,xb1,xb2,xb3, tb0,tb1,tb2,tb3, i);   // B loads in flight...
            i += stride4;
            PROC4(xa0, ta0); PROC4(xa1, ta1); PROC4(xa2, ta2); PROC4(xa3, ta3); // ...over A compute
            if (i + 3 * stride >= nvec) {   // B is the last full group
                PROC4(xb0, tb0); PROC4(xb1, tb1); PROC4(xb2, tb2); PROC4(xb3, tb3);
                break;
            }
            LOADG(xa0,xa1,xa2,xa3, ta0,ta1,ta2,ta3, i);   // A loads in flight...
            i += stride4;
            PROC4(xb0, tb0); PROC4(xb1, tb1); PROC4(xb2, tb2); PROC4(xb3, tb3); // ...over B compute
        }
    }
    // leftover full chunks (when nvec not divisible by 4*stride)
    for (; i < nvec; i += stride) {
        f32x4 x = ldnt(in4 + i);
        i32x4 t = tg4[i];
        PROC4(x, t);
    }

    // scalar tail (n not divisible by 4) — block 0 only
    const long long tail0 = (long long)nvec << 2;
    if (blockIdx.x == 0) {
        for (long long j = tail0 + threadIdx.x; j < n; j += blockDim.x) {
            float x = in[j];
            int   t = tg[j];
            PROC(x, t);
        }
    }
#undef LOADG
#undef PROC4
#undef PROC

    // wave-64 reduction in double
    double dc1 = (double)lc1, ds1 = (double)ls1;
    double dqa = (double)lqa, dq1 = (double)lq1;
    for (int off = 32; off > 0; off >>= 1) {
        dc1 += __shfl_down(dc1, off, 64);
        ds1 += __shfl_down(ds1, off, 64);
        dqa += __shfl_down(dqa, off, 64);
        dq1 += __shfl_down(dq1, off, 64);
    }

    __shared__ double sm[4][4];  // [wave][acc]
    const int wid  = threadIdx.x >> 6;
    const int lane = threadIdx.x & 63;
    if (lane == 0) {
        sm[wid][0] = dc1; sm[wid][1] = ds1;
        sm[wid][2] = dqa; sm[wid][3] = dq1;
    }
    __syncthreads();
    if (threadIdx.x == 0) {
        double a0 = 0, a1 = 0, a2 = 0, a3 = 0;
        for (int w = 0; w < 4; ++w) {
            a0 += sm[w][0]; a1 += sm[w][1];
            a2 += sm[w][2]; a3 += sm[w][3];
        }
        double* p = ws + (size_t)blockIdx.x * 4;
        p[0] = a0; p[1] = a1; p[2] = a2; p[3] = a3;  // plain stores, no atomics
    }
}

// Stage 2: one 1024-thread block reduces nblocks*4 doubles and writes the loss.
__global__ __launch_bounds__(1024) void balanced_loss_stage2(
    const double* __restrict__ ws, int nblocks,
    float* __restrict__ out, long long n)
{
    double c1 = 0, s1 = 0, qa = 0, q1 = 0;
    for (int b = threadIdx.x; b < nblocks; b += blockDim.x) {
        const double* p = ws + (size_t)b * 4;
        c1 += p[0]; s1 += p[1]; qa += p[2]; q1 += p[3];
    }
    for (int off = 32; off > 0; off >>= 1) {
        c1 += __shfl_down(c1, off, 64);
        s1 += __shfl_down(s1, off, 64);
        qa += __shfl_down(qa, off, 64);
        q1 += __shfl_down(q1, off, 64);
    }
    __shared__ double sm[16][4];
    const int wid  = threadIdx.x >> 6;
    const int lane = threadIdx.x & 63;
    if (lane == 0) {
        sm[wid][0] = c1; sm[wid][1] = s1;
        sm[wid][2] = qa; sm[wid][3] = q1;
    }
    __syncthreads();
    if (threadIdx.x == 0) {
        double a0 = 0, a1 = 0, a2 = 0, a3 = 0;
        const int nw = blockDim.x >> 6;
        for (int w = 0; w < nw; ++w) {
            a0 += sm[w][0]; a1 += sm[w][1];
            a2 += sm[w][2]; a3 += sm[w][3];
        }
        double cc1 = a0;
        double cc0 = (double)n - cc1;
        double w0 = 1.0 / ((cc0 + SMOOTH) * (cc0 + SMOOTH));
        double w1 = 1.0 / ((cc1 + SMOOTH) * (cc1 + SMOOTH));
        double q0 = a2 - a3;                     // q_all - q1
        double I  = w1 * a1;
        double D  = w0 * q0 + w1 * (a3 + cc1);   // sum(t*t | t==1) == c1
        out[0] = (float)(1.0 - (2.0 * I + SMOOTH) / (D + SMOOTH));
    }
}

extern "C" void kernel_launch(void* const* d_in, const int* in_sizes, int n_in,
                              void* d_out, int out_size, void* d_ws, size_t ws_size,
                              hipStream_t stream) {
    const float* in = (const float*)d_in[0];
    const int*   tg = (const int*)d_in[1];
    long long n = (long long)in_sizes[0];
    double* ws = (double*)d_ws;

    const int block = 256;
    const int grid  = 1024;  // 4 blocks/CU resident (VGPR~100 tier), one dispatch round

    balanced_loss_stage1<<<grid, block, 0, stream>>>(in, tg, n, ws);
    balanced_loss_stage2<<<1, 1024, 0, stream>>>(ws, grid, (float*)d_out, n);
}